// Round 1
// baseline (2057.613 us; speedup 1.0000x reference)
//
#include <hip/hip_runtime.h>

#define NB  8
#define NPT 4096
#define NS  1024
#define NK  32
#define DIN 6

// ---------------------------------------------------------------------------
// BN (eval mode) + ReLU applied to a linear accumulator.
// reference: x = acc + b; x = g*(x-m)*rsqrt(v+eps)+be; relu
// ---------------------------------------------------------------------------
__device__ __forceinline__ float bnrelu(float acc, const float* __restrict__ bb,
                                        const float* __restrict__ gg,
                                        const float* __restrict__ be,
                                        const float* __restrict__ mm,
                                        const float* __restrict__ vv, int oc) {
  float t = (acc + bb[oc]) - mm[oc];
  float val = gg[oc] * t * rsqrtf(vv[oc] + 1e-5f) + be[oc];
  return fmaxf(val, 0.0f);
}

// ---------------------------------------------------------------------------
// Kernel 1: farthest point sampling. One block per batch. 512 threads,
// 8 contiguous points per thread held in registers. Exact fp32 op order
// (no fma contraction) to reproduce the reference argmax selection.
// ---------------------------------------------------------------------------
__global__ __launch_bounds__(512) void fps_kernel(const float* __restrict__ xyz,
                                                  int* __restrict__ fps_idx,
                                                  float* __restrict__ nxyz,
                                                  float* __restrict__ out0) {
  const int b = blockIdx.x;
  const int t = threadIdx.x;
  const int lane = t & 63, wid = t >> 6;
  const float* xb = xyz + (size_t)b * 3 * NPT;

  float px[8], py[8], pz[8], dist[8];
  const int base = t * 8;
#pragma unroll
  for (int j = 0; j < 8; ++j) {
    px[j] = xb[base + j];
    py[j] = xb[NPT + base + j];
    pz[j] = xb[2 * NPT + base + j];
    dist[j] = 1e10f;
  }

  __shared__ float s_rv[8][4];  // per wave: val, x, y, z
  __shared__ int s_ri[8];

  int far = 0;
  float cx = xb[0], cy = xb[NPT], cz = xb[2 * NPT];

  for (int s = 0; s < NS; ++s) {
    // emit current farthest point (reference emits carry BEFORE update)
    if (t < 3) {
      float vv = (t == 0) ? cx : ((t == 1) ? cy : cz);
      out0[((size_t)b * 3 + t) * NS + s] = vv;
      nxyz[((size_t)b * NS + s) * 3 + t] = vv;
    }
    if (t == 3) fps_idx[b * NS + s] = far;

    // min-update distances + per-thread first-max (ascending index order)
    float bv = -1.0f, bx = 0.f, by = 0.f, bz = 0.f;
    int bi = 0;
#pragma unroll
    for (int j = 0; j < 8; ++j) {
      float dx = __fsub_rn(px[j], cx);
      float dy = __fsub_rn(py[j], cy);
      float dz = __fsub_rn(pz[j], cz);
      float d = __fadd_rn(__fadd_rn(__fmul_rn(dx, dx), __fmul_rn(dy, dy)),
                          __fmul_rn(dz, dz));
      float nd = fminf(dist[j], d);
      dist[j] = nd;
      if (nd > bv) { bv = nd; bi = base + j; bx = px[j]; by = py[j]; bz = pz[j]; }
    }

    // wave-level max; first set lane = smallest index (contiguous ownership)
    float mv = bv;
#pragma unroll
    for (int off = 32; off > 0; off >>= 1) mv = fmaxf(mv, __shfl_xor(mv, off));
    unsigned long long mmask = __ballot(bv == mv);
    int src = __ffsll((unsigned long long)mmask) - 1;
    int wi = __shfl(bi, src);
    float wx = __shfl(bx, src);
    float wy = __shfl(by, src);
    float wz = __shfl(bz, src);

    __syncthreads();  // previous iteration's slot reads complete
    if (lane == 0) {
      s_rv[wid][0] = mv; s_rv[wid][1] = wx; s_rv[wid][2] = wy; s_rv[wid][3] = wz;
      s_ri[wid] = wi;
    }
    __syncthreads();

    // cross-wave scan (ascending wave = ascending index; strict > keeps first)
    float bestv = -1.0f;
    int bw = 0;
#pragma unroll
    for (int w = 0; w < 8; ++w) {
      float v = s_rv[w][0];
      if (v > bestv) { bestv = v; bw = w; }
    }
    far = s_ri[bw];
    cx = s_rv[bw][1]; cy = s_rv[bw][2]; cz = s_rv[bw][3];
  }
}

// ---------------------------------------------------------------------------
// Kernel 2: center-point MLP + center half of attention scores.
// ceA[bs][oc] = sum_c center_out[c] * a[3+c][oc]
// One 64-thread block per query.
// ---------------------------------------------------------------------------
__global__ __launch_bounds__(64) void center_kernel(
    const float* __restrict__ points, const float* __restrict__ nxyz,
    const int* __restrict__ fps_idx,
    const float* __restrict__ w0, const float* __restrict__ b0,
    const float* __restrict__ g0, const float* __restrict__ be0,
    const float* __restrict__ m0, const float* __restrict__ v0,
    const float* __restrict__ w1, const float* __restrict__ b1,
    const float* __restrict__ g1, const float* __restrict__ be1,
    const float* __restrict__ m1, const float* __restrict__ v1,
    const float* __restrict__ w2, const float* __restrict__ b2,
    const float* __restrict__ g2, const float* __restrict__ be2,
    const float* __restrict__ m2, const float* __restrict__ v2,
    const float* __restrict__ a, float* __restrict__ ceA) {
  const int bs = blockIdx.x;
  const int b = bs >> 10;
  const int t = threadIdx.x;

  __shared__ float ci[9];
  __shared__ float ch1[64];
  __shared__ float ch2[64];
  __shared__ float ch3[128];

  if (t < 9) {
    ci[t] = (t < 3) ? nxyz[(size_t)bs * 3 + t]
                    : points[((size_t)b * DIN + (t - 3)) * NPT + fps_idx[bs]];
  }
  __syncthreads();
  {
    float acc = 0.f;
#pragma unroll
    for (int c = 0; c < 9; ++c) acc = fmaf(ci[c], w0[t * 9 + c], acc);
    ch1[t] = bnrelu(acc, b0, g0, be0, m0, v0, t);
  }
  __syncthreads();
  {
    float acc = 0.f;
#pragma unroll 8
    for (int c = 0; c < 64; ++c) acc = fmaf(ch1[c], w1[t * 64 + c], acc);
    ch2[t] = bnrelu(acc, b1, g1, be1, m1, v1, t);
  }
  __syncthreads();
  for (int oc = t; oc < 128; oc += 64) {
    float acc = 0.f;
#pragma unroll 8
    for (int c = 0; c < 64; ++c) acc = fmaf(ch2[c], w2[oc * 64 + c], acc);
    ch3[oc] = bnrelu(acc, b2, g2, be2, m2, v2, oc);
  }
  __syncthreads();
  for (int oc = t; oc < 128; oc += 64) {
    float acc = 0.f;
#pragma unroll 8
    for (int c = 0; c < 128; ++c) acc = fmaf(ch3[c], a[(3 + c) * 128 + oc], acc);
    ceA[(size_t)bs * 128 + oc] = acc;
  }
}

// ---------------------------------------------------------------------------
// Kernel 3: per-query fused ball query + gather + neighbor MLP + attention.
// One 256-thread block per query (8192 blocks).
// Thread mapping for GEMV phases: k = t&31 (neighbor row per lane),
// ocg = t>>5 (register-blocked output channels) -> per-lane-distinct LDS b128.
// ---------------------------------------------------------------------------
__global__ __launch_bounds__(256) void main_kernel(
    const float* __restrict__ xyz, const float* __restrict__ points,
    const float* __restrict__ nxyz, const float* __restrict__ ceA,
    const float* __restrict__ w0, const float* __restrict__ b0,
    const float* __restrict__ g0, const float* __restrict__ be0,
    const float* __restrict__ m0, const float* __restrict__ v0,
    const float* __restrict__ w1, const float* __restrict__ b1,
    const float* __restrict__ g1, const float* __restrict__ be1,
    const float* __restrict__ m1, const float* __restrict__ v1,
    const float* __restrict__ w2, const float* __restrict__ b2,
    const float* __restrict__ g2, const float* __restrict__ be2,
    const float* __restrict__ m2, const float* __restrict__ v2,
    const float* __restrict__ a, float* __restrict__ out1) {
  const int bs = blockIdx.x;
  const int b = bs >> 10;
  const int s = bs & 1023;
  const int t = threadIdx.x;
  const int lane = t & 63;
  const int wid = t >> 6;

  __shared__ int s_idx[NK];
  __shared__ int s_cnt[4];
  __shared__ float s_nb[32 * 12];   // [k][12]: gx,gy,gz (rel), p0..p5, pad
  __shared__ float s_h1[32 * 68];   // layer1 out, padded stride
  __shared__ float s_h2[32 * 68];   // layer2 out
  __shared__ float s_u[32 * 132];   // [k]: h3(128), gx,gy,gz, 0

  const float cx = nxyz[(size_t)bs * 3 + 0];
  const float cy = nxyz[(size_t)bs * 3 + 1];
  const float cz = nxyz[(size_t)bs * 3 + 2];

  // ---- ball query: first 32 in-radius indices in ascending order ----
  {
    const float R2 = (float)(0.15 * 0.15);  // python f64 product -> f32
    float s2c = __fadd_rn(__fadd_rn(__fmul_rn(cx, cx), __fmul_rn(cy, cy)),
                          __fmul_rn(cz, cz));
    int filled = 0;
    for (int g = 0; g < 16; ++g) {
      int n = g * 256 + t;
      float x = xyz[((size_t)b * 3 + 0) * NPT + n];
      float y = xyz[((size_t)b * 3 + 1) * NPT + n];
      float z = xyz[((size_t)b * 3 + 2) * NPT + n];
      float pn2 = __fadd_rn(__fadd_rn(__fmul_rn(x, x), __fmul_rn(y, y)),
                            __fmul_rn(z, z));
      float dot = fmaf(cz, z, fmaf(cy, y, __fmul_rn(cx, x)));
      float sqr = __fsub_rn(__fadd_rn(s2c, pn2), __fmul_rn(2.0f, dot));
      bool hit = !(sqr > R2);
      unsigned long long mmask = __ballot(hit);
      if (lane == 0) s_cnt[wid] = __popcll(mmask);
      __syncthreads();
      int c0 = s_cnt[0], c1 = s_cnt[1], c2 = s_cnt[2], c3 = s_cnt[3];
      int basew = filled + ((wid > 0) ? c0 : 0) + ((wid > 1) ? c1 : 0) +
                  ((wid > 2) ? c2 : 0);
      int pos = basew + __popcll(mmask & ((1ull << lane) - 1ull));
      if (hit && pos < NK) s_idx[pos] = n;
      filled += c0 + c1 + c2 + c3;
      __syncthreads();
      if (filled >= NK) break;
    }
    int klim = (filled < NK) ? filled : NK;
    if (t >= klim && t < NK) s_idx[t] = s_idx[0];  // pad misses with first hit
    __syncthreads();
  }

  // ---- gather neighbor features: [rel_xyz(3), points(6)] ----
  for (int tt = t; tt < 32 * 12; tt += 256) {
    int k = tt / 12;
    int c = tt - k * 12;
    float v = 0.f;
    int n = s_idx[k];
    if (c < 3) {
      float pv = xyz[((size_t)b * 3 + c) * NPT + n];
      float ctr = (c == 0) ? cx : ((c == 1) ? cy : cz);
      v = __fsub_rn(pv, ctr);
    } else if (c < 9) {
      v = points[((size_t)b * DIN + (c - 3)) * NPT + n];
    }
    s_nb[k * 12 + c] = v;
  }
  __syncthreads();

  const int k = t & 31;
  const int ocg = t >> 5;  // 0..7

  // ---- layer 1: 9 -> 64 ----
  {
    const float4* row = (const float4*)&s_nb[k * 12];
    float4 r0 = row[0], r1 = row[1], r2 = row[2];
    float in0[12] = {r0.x, r0.y, r0.z, r0.w, r1.x, r1.y,
                     r1.z, r1.w, r2.x, r2.y, r2.z, r2.w};
    int oc0 = ocg * 8;
    float acc[8];
#pragma unroll
    for (int j = 0; j < 8; ++j) {
      float a0 = 0.f;
#pragma unroll
      for (int c = 0; c < 9; ++c) a0 = fmaf(in0[c], w0[(oc0 + j) * 9 + c], a0);
      acc[j] = bnrelu(a0, b0, g0, be0, m0, v0, oc0 + j);
    }
    float4* orow = (float4*)&s_h1[k * 68 + oc0];
    orow[0] = make_float4(acc[0], acc[1], acc[2], acc[3]);
    orow[1] = make_float4(acc[4], acc[5], acc[6], acc[7]);
  }
  __syncthreads();

  // ---- layer 2: 64 -> 64 ----
  {
    int oc0 = ocg * 8;
    float acc[8] = {0.f, 0.f, 0.f, 0.f, 0.f, 0.f, 0.f, 0.f};
    const float4* row = (const float4*)&s_h1[k * 68];
#pragma unroll 4
    for (int c4 = 0; c4 < 16; ++c4) {
      float4 hv = row[c4];
#pragma unroll
      for (int j = 0; j < 8; ++j) {
        float4 wv = *(const float4*)&w1[(oc0 + j) * 64 + c4 * 4];
        acc[j] = fmaf(hv.x, wv.x, acc[j]);
        acc[j] = fmaf(hv.y, wv.y, acc[j]);
        acc[j] = fmaf(hv.z, wv.z, acc[j]);
        acc[j] = fmaf(hv.w, wv.w, acc[j]);
      }
    }
#pragma unroll
    for (int j = 0; j < 8; ++j)
      acc[j] = bnrelu(acc[j], b1, g1, be1, m1, v1, oc0 + j);
    float4* orow = (float4*)&s_h2[k * 68 + oc0];
    orow[0] = make_float4(acc[0], acc[1], acc[2], acc[3]);
    orow[1] = make_float4(acc[4], acc[5], acc[6], acc[7]);
  }
  __syncthreads();

  // ---- layer 3: 64 -> 128, output into u[k][0..127]; u[k][128..130]=g ----
  {
    int oc0 = ocg * 16;
    float acc[16];
#pragma unroll
    for (int j = 0; j < 16; ++j) acc[j] = 0.f;
    const float4* row = (const float4*)&s_h2[k * 68];
#pragma unroll 2
    for (int c4 = 0; c4 < 16; ++c4) {
      float4 hv = row[c4];
#pragma unroll
      for (int j = 0; j < 16; ++j) {
        float4 wv = *(const float4*)&w2[(oc0 + j) * 64 + c4 * 4];
        acc[j] = fmaf(hv.x, wv.x, acc[j]);
        acc[j] = fmaf(hv.y, wv.y, acc[j]);
        acc[j] = fmaf(hv.z, wv.z, acc[j]);
        acc[j] = fmaf(hv.w, wv.w, acc[j]);
      }
    }
#pragma unroll
    for (int j = 0; j < 16; ++j)
      acc[j] = bnrelu(acc[j], b2, g2, be2, m2, v2, oc0 + j);
    float4* orow = (float4*)&s_u[k * 132 + oc0];
    orow[0] = make_float4(acc[0], acc[1], acc[2], acc[3]);
    orow[1] = make_float4(acc[4], acc[5], acc[6], acc[7]);
    orow[2] = make_float4(acc[8], acc[9], acc[10], acc[11]);
    orow[3] = make_float4(acc[12], acc[13], acc[14], acc[15]);
    if (t < 32) {
      s_u[t * 132 + 128] = s_nb[t * 12 + 0];
      s_u[t * 132 + 129] = s_nb[t * 12 + 1];
      s_u[t * 132 + 130] = s_nb[t * 12 + 2];
      s_u[t * 132 + 131] = 0.f;
    }
  }
  __syncthreads();

  // ---- attention: T[k][oc] = sum_r u[k][r]*a_perm[r][oc];
  //      e = leaky(ceA - T); softmax over k (half-wave); out = sum att*h3 ----
  {
    int oc0 = ocg * 16;
    float acc[16];
#pragma unroll
    for (int j = 0; j < 16; ++j) acc[j] = 0.f;
    const float4* urow = (const float4*)&s_u[k * 132];
    for (int r4 = 0; r4 < 33; ++r4) {
      float4 uv = urow[r4];
      int r = r4 * 4;
#pragma unroll
      for (int cc = 0; cc < 4; ++cc) {
        int rr = r + cc;
        int arow = (rr < 128) ? (rr + 3) : (rr - 128);  // rr==131 hits a[3]*0
        float uc = (cc == 0) ? uv.x : (cc == 1) ? uv.y : (cc == 2) ? uv.z : uv.w;
        const float4* arp = (const float4*)&a[arow * 128 + oc0];
#pragma unroll
        for (int j4 = 0; j4 < 4; ++j4) {
          float4 av = arp[j4];
          acc[j4 * 4 + 0] = fmaf(uc, av.x, acc[j4 * 4 + 0]);
          acc[j4 * 4 + 1] = fmaf(uc, av.y, acc[j4 * 4 + 1]);
          acc[j4 * 4 + 2] = fmaf(uc, av.z, acc[j4 * 4 + 2]);
          acc[j4 * 4 + 3] = fmaf(uc, av.w, acc[j4 * 4 + 3]);
        }
      }
    }

    float ce[16], h3[16];
#pragma unroll
    for (int j4 = 0; j4 < 4; ++j4) {
      float4 cv = *(const float4*)&ceA[(size_t)bs * 128 + oc0 + j4 * 4];
      ce[j4 * 4 + 0] = cv.x; ce[j4 * 4 + 1] = cv.y;
      ce[j4 * 4 + 2] = cv.z; ce[j4 * 4 + 3] = cv.w;
      float4 hv = *(const float4*)&s_u[k * 132 + oc0 + j4 * 4];
      h3[j4 * 4 + 0] = hv.x; h3[j4 * 4 + 1] = hv.y;
      h3[j4 * 4 + 2] = hv.z; h3[j4 * 4 + 3] = hv.w;
    }

    float* outb = out1 + (size_t)b * 128 * NS + s;
#pragma unroll
    for (int j = 0; j < 16; ++j) {
      float e = ce[j] - acc[j];
      e = (e >= 0.f) ? e : 0.2f * e;  // leaky relu, alpha=0.2
      float mx = e;
#pragma unroll
      for (int off = 16; off > 0; off >>= 1)
        mx = fmaxf(mx, __shfl_xor(mx, off));
      float p = expf(e - mx);
      float num = p * h3[j];
      float den = p;
#pragma unroll
      for (int off = 16; off > 0; off >>= 1) {
        num += __shfl_xor(num, off);
        den += __shfl_xor(den, off);
      }
      if (k == 0) outb[(size_t)(oc0 + j) * NS] = num / den;
    }
  }
}

// ---------------------------------------------------------------------------
extern "C" void kernel_launch(void* const* d_in, const int* in_sizes, int n_in,
                              void* d_out, int out_size, void* d_ws,
                              size_t ws_size, hipStream_t stream) {
  (void)in_sizes; (void)n_in; (void)out_size; (void)ws_size;
  const float* xyz = (const float*)d_in[0];
  const float* points = (const float*)d_in[1];
  const float* w0 = (const float*)d_in[2];
  const float* b0 = (const float*)d_in[3];
  const float* g0 = (const float*)d_in[4];
  const float* be0 = (const float*)d_in[5];
  const float* m0 = (const float*)d_in[6];
  const float* v0 = (const float*)d_in[7];
  const float* w1 = (const float*)d_in[8];
  const float* b1 = (const float*)d_in[9];
  const float* g1 = (const float*)d_in[10];
  const float* be1 = (const float*)d_in[11];
  const float* m1 = (const float*)d_in[12];
  const float* v1 = (const float*)d_in[13];
  const float* w2 = (const float*)d_in[14];
  const float* b2 = (const float*)d_in[15];
  const float* g2 = (const float*)d_in[16];
  const float* be2 = (const float*)d_in[17];
  const float* m2 = (const float*)d_in[18];
  const float* v2 = (const float*)d_in[19];
  const float* a = (const float*)d_in[20];

  float* out0 = (float*)d_out;                  // [B,3,S]
  float* out1 = out0 + (size_t)NB * 3 * NS;     // [B,128,S]

  int* fps = (int*)d_ws;                                   // 8192 ints
  float* nxyz = (float*)((char*)d_ws + 32768);             // 8192*3 floats
  float* ceA = (float*)((char*)d_ws + 32768 + 98304);      // 8192*128 floats

  fps_kernel<<<NB, 512, 0, stream>>>(xyz, fps, nxyz, out0);
  center_kernel<<<NB * NS, 64, 0, stream>>>(points, nxyz, fps,
      w0, b0, g0, be0, m0, v0, w1, b1, g1, be1, m1, v1,
      w2, b2, g2, be2, m2, v2, a, ceA);
  main_kernel<<<NB * NS, 256, 0, stream>>>(xyz, points, nxyz, ceA,
      w0, b0, g0, be0, m0, v0, w1, b1, g1, be1, m1, v1,
      w2, b2, g2, be2, m2, v2, a, out1);
}

// Round 2
// 1920.888 us; speedup vs baseline: 1.0712x; 1.0712x over previous
//
#include <hip/hip_runtime.h>

#define NB  8
#define NPT 4096
#define NS  1024
#define NK  32
#define DIN 6

// ---------------------------------------------------------------------------
// BN (eval mode) + ReLU applied to a linear accumulator.
// ---------------------------------------------------------------------------
__device__ __forceinline__ float bnrelu(float acc, const float* __restrict__ bb,
                                        const float* __restrict__ gg,
                                        const float* __restrict__ be,
                                        const float* __restrict__ mm,
                                        const float* __restrict__ vv, int oc) {
  float t = (acc + bb[oc]) - mm[oc];
  float val = gg[oc] * t * rsqrtf(vv[oc] + 1e-5f) + be[oc];
  return fmaxf(val, 0.0f);
}

// ---------------------------------------------------------------------------
// Kernel 1: farthest point sampling. One block per batch, 512 threads × 8 pts.
// v2: all per-step outputs buffered in LDS (no vmcnt on critical path),
// double-buffered reduction slots (1 barrier/step), register-resident
// cross-wave scan. Selection semantics identical to the verified v1:
// per-thread first-max (ascending j) -> wave ffs(ballot) -> ascending-wave
// strict-> scan; distances in exact __f*_rn order (no fma contraction).
// ---------------------------------------------------------------------------
__global__ __launch_bounds__(512) void fps_kernel(const float* __restrict__ xyz,
                                                  int* __restrict__ fps_idx,
                                                  float* __restrict__ nxyz,
                                                  float* __restrict__ out0) {
  const int b = blockIdx.x;
  const int t = threadIdx.x;
  const int lane = t & 63, wid = t >> 6;
  const float* xb = xyz + (size_t)b * 3 * NPT;

  float px[8], py[8], pz[8], dist[8];
  const int base = t * 8;
#pragma unroll
  for (int j = 0; j < 8; ++j) {
    px[j] = xb[base + j];
    py[j] = xb[NPT + base + j];
    pz[j] = xb[2 * NPT + base + j];
    dist[j] = 1e10f;
  }

  __shared__ float s_rv[2][8][4];  // parity-buffered: per wave val,x,y,z
  __shared__ int s_ri[2][8];
  __shared__ float s_ox[NS], s_oy[NS], s_oz[NS];
  __shared__ int s_fi[NS];

  int far = 0;
  float cx = xb[0], cy = xb[NPT], cz = xb[2 * NPT];

  for (int s = 0; s < NS; ++s) {
    // record current farthest point into LDS (flushed to global at the end)
    if (t == 0) {
      s_ox[s] = cx; s_oy[s] = cy; s_oz[s] = cz; s_fi[s] = far;
    }

    // min-update distances + per-thread first-max (ascending index order)
    float bv = -1.0f, bx = 0.f, by = 0.f, bz = 0.f;
    int bi = 0;
#pragma unroll
    for (int j = 0; j < 8; ++j) {
      float dx = __fsub_rn(px[j], cx);
      float dy = __fsub_rn(py[j], cy);
      float dz = __fsub_rn(pz[j], cz);
      float d = __fadd_rn(__fadd_rn(__fmul_rn(dx, dx), __fmul_rn(dy, dy)),
                          __fmul_rn(dz, dz));
      float nd = fminf(dist[j], d);
      dist[j] = nd;
      if (nd > bv) { bv = nd; bi = base + j; bx = px[j]; by = py[j]; bz = pz[j]; }
    }

    // wave-level max; first set lane = smallest index (contiguous ownership)
    float mv = bv;
#pragma unroll
    for (int off = 32; off > 0; off >>= 1) mv = fmaxf(mv, __shfl_xor(mv, off));
    unsigned long long mmask = __ballot(bv == mv);
    int src = __ffsll(mmask) - 1;
    int wi = __shfl(bi, src);
    float wx = __shfl(bx, src);
    float wy = __shfl(by, src);
    float wz = __shfl(bz, src);

    const int p = s & 1;
    if (lane == 0) {
      s_rv[p][wid][0] = mv; s_rv[p][wid][1] = wx;
      s_rv[p][wid][2] = wy; s_rv[p][wid][3] = wz;
      s_ri[p][wid] = wi;
    }
    __syncthreads();

    // load all wave results into registers (parallel LDS reads), then scan
    float rv[8], rx[8], ry[8], rz[8];
    int ri[8];
#pragma unroll
    for (int w = 0; w < 8; ++w) {
      float4 q = *(const float4*)&s_rv[p][w][0];
      rv[w] = q.x; rx[w] = q.y; ry[w] = q.z; rz[w] = q.w;
      ri[w] = s_ri[p][w];
    }
    float bestv = rv[0];
    float ncx = rx[0], ncy = ry[0], ncz = rz[0];
    int nfar = ri[0];
#pragma unroll
    for (int w = 1; w < 8; ++w) {
      bool better = rv[w] > bestv;  // strict > keeps first (ascending wave)
      bestv = better ? rv[w] : bestv;
      ncx = better ? rx[w] : ncx;
      ncy = better ? ry[w] : ncy;
      ncz = better ? rz[w] : ncz;
      nfar = better ? ri[w] : nfar;
    }
    far = nfar; cx = ncx; cy = ncy; cz = ncz;
  }

  __syncthreads();
  // flush buffered outputs to global
  for (int i = t; i < NS; i += 512) {
    float X = s_ox[i], Y = s_oy[i], Z = s_oz[i];
    out0[((size_t)b * 3 + 0) * NS + i] = X;
    out0[((size_t)b * 3 + 1) * NS + i] = Y;
    out0[((size_t)b * 3 + 2) * NS + i] = Z;
    nxyz[((size_t)b * NS + i) * 3 + 0] = X;
    nxyz[((size_t)b * NS + i) * 3 + 1] = Y;
    nxyz[((size_t)b * NS + i) * 3 + 2] = Z;
    fps_idx[b * NS + i] = s_fi[i];
  }
}

// ---------------------------------------------------------------------------
// Kernel 2: center-point MLP + center half of attention scores. (unchanged)
// ---------------------------------------------------------------------------
__global__ __launch_bounds__(64) void center_kernel(
    const float* __restrict__ points, const float* __restrict__ nxyz,
    const int* __restrict__ fps_idx,
    const float* __restrict__ w0, const float* __restrict__ b0,
    const float* __restrict__ g0, const float* __restrict__ be0,
    const float* __restrict__ m0, const float* __restrict__ v0,
    const float* __restrict__ w1, const float* __restrict__ b1,
    const float* __restrict__ g1, const float* __restrict__ be1,
    const float* __restrict__ m1, const float* __restrict__ v1,
    const float* __restrict__ w2, const float* __restrict__ b2,
    const float* __restrict__ g2, const float* __restrict__ be2,
    const float* __restrict__ m2, const float* __restrict__ v2,
    const float* __restrict__ a, float* __restrict__ ceA) {
  const int bs = blockIdx.x;
  const int b = bs >> 10;
  const int t = threadIdx.x;

  __shared__ float ci[9];
  __shared__ float ch1[64];
  __shared__ float ch2[64];
  __shared__ float ch3[128];

  if (t < 9) {
    ci[t] = (t < 3) ? nxyz[(size_t)bs * 3 + t]
                    : points[((size_t)b * DIN + (t - 3)) * NPT + fps_idx[bs]];
  }
  __syncthreads();
  {
    float acc = 0.f;
#pragma unroll
    for (int c = 0; c < 9; ++c) acc = fmaf(ci[c], w0[t * 9 + c], acc);
    ch1[t] = bnrelu(acc, b0, g0, be0, m0, v0, t);
  }
  __syncthreads();
  {
    float acc = 0.f;
#pragma unroll 8
    for (int c = 0; c < 64; ++c) acc = fmaf(ch1[c], w1[t * 64 + c], acc);
    ch2[t] = bnrelu(acc, b1, g1, be1, m1, v1, t);
  }
  __syncthreads();
  for (int oc = t; oc < 128; oc += 64) {
    float acc = 0.f;
#pragma unroll 8
    for (int c = 0; c < 64; ++c) acc = fmaf(ch2[c], w2[oc * 64 + c], acc);
    ch3[oc] = bnrelu(acc, b2, g2, be2, m2, v2, oc);
  }
  __syncthreads();
  for (int oc = t; oc < 128; oc += 64) {
    float acc = 0.f;
#pragma unroll 8
    for (int c = 0; c < 128; ++c) acc = fmaf(ch3[c], a[(3 + c) * 128 + oc], acc);
    ceA[(size_t)bs * 128 + oc] = acc;
  }
}

// ---------------------------------------------------------------------------
// Kernel 3: per-query fused ball query + gather + neighbor MLP + attention.
// (unchanged)
// ---------------------------------------------------------------------------
__global__ __launch_bounds__(256) void main_kernel(
    const float* __restrict__ xyz, const float* __restrict__ points,
    const float* __restrict__ nxyz, const float* __restrict__ ceA,
    const float* __restrict__ w0, const float* __restrict__ b0,
    const float* __restrict__ g0, const float* __restrict__ be0,
    const float* __restrict__ m0, const float* __restrict__ v0,
    const float* __restrict__ w1, const float* __restrict__ b1,
    const float* __restrict__ g1, const float* __restrict__ be1,
    const float* __restrict__ m1, const float* __restrict__ v1,
    const float* __restrict__ w2, const float* __restrict__ b2,
    const float* __restrict__ g2, const float* __restrict__ be2,
    const float* __restrict__ m2, const float* __restrict__ v2,
    const float* __restrict__ a, float* __restrict__ out1) {
  const int bs = blockIdx.x;
  const int b = bs >> 10;
  const int s = bs & 1023;
  const int t = threadIdx.x;
  const int lane = t & 63;
  const int wid = t >> 6;

  __shared__ int s_idx[NK];
  __shared__ int s_cnt[4];
  __shared__ float s_nb[32 * 12];   // [k][12]: gx,gy,gz (rel), p0..p5, pad
  __shared__ float s_h1[32 * 68];   // layer1 out, padded stride
  __shared__ float s_h2[32 * 68];   // layer2 out
  __shared__ float s_u[32 * 132];   // [k]: h3(128), gx,gy,gz, 0

  const float cx = nxyz[(size_t)bs * 3 + 0];
  const float cy = nxyz[(size_t)bs * 3 + 1];
  const float cz = nxyz[(size_t)bs * 3 + 2];

  // ---- ball query: first 32 in-radius indices in ascending order ----
  {
    const float R2 = (float)(0.15 * 0.15);  // python f64 product -> f32
    float s2c = __fadd_rn(__fadd_rn(__fmul_rn(cx, cx), __fmul_rn(cy, cy)),
                          __fmul_rn(cz, cz));
    int filled = 0;
    for (int g = 0; g < 16; ++g) {
      int n = g * 256 + t;
      float x = xyz[((size_t)b * 3 + 0) * NPT + n];
      float y = xyz[((size_t)b * 3 + 1) * NPT + n];
      float z = xyz[((size_t)b * 3 + 2) * NPT + n];
      float pn2 = __fadd_rn(__fadd_rn(__fmul_rn(x, x), __fmul_rn(y, y)),
                            __fmul_rn(z, z));
      float dot = fmaf(cz, z, fmaf(cy, y, __fmul_rn(cx, x)));
      float sqr = __fsub_rn(__fadd_rn(s2c, pn2), __fmul_rn(2.0f, dot));
      bool hit = !(sqr > R2);
      unsigned long long mmask = __ballot(hit);
      if (lane == 0) s_cnt[wid] = __popcll(mmask);
      __syncthreads();
      int c0 = s_cnt[0], c1 = s_cnt[1], c2 = s_cnt[2], c3 = s_cnt[3];
      int basew = filled + ((wid > 0) ? c0 : 0) + ((wid > 1) ? c1 : 0) +
                  ((wid > 2) ? c2 : 0);
      int pos = basew + __popcll(mmask & ((1ull << lane) - 1ull));
      if (hit && pos < NK) s_idx[pos] = n;
      filled += c0 + c1 + c2 + c3;
      __syncthreads();
      if (filled >= NK) break;
    }
    int klim = (filled < NK) ? filled : NK;
    if (t >= klim && t < NK) s_idx[t] = s_idx[0];  // pad misses with first hit
    __syncthreads();
  }

  // ---- gather neighbor features: [rel_xyz(3), points(6)] ----
  for (int tt = t; tt < 32 * 12; tt += 256) {
    int k = tt / 12;
    int c = tt - k * 12;
    float v = 0.f;
    int n = s_idx[k];
    if (c < 3) {
      float pv = xyz[((size_t)b * 3 + c) * NPT + n];
      float ctr = (c == 0) ? cx : ((c == 1) ? cy : cz);
      v = __fsub_rn(pv, ctr);
    } else if (c < 9) {
      v = points[((size_t)b * DIN + (c - 3)) * NPT + n];
    }
    s_nb[k * 12 + c] = v;
  }
  __syncthreads();

  const int k = t & 31;
  const int ocg = t >> 5;  // 0..7

  // ---- layer 1: 9 -> 64 ----
  {
    const float4* row = (const float4*)&s_nb[k * 12];
    float4 r0 = row[0], r1 = row[1], r2 = row[2];
    float in0[12] = {r0.x, r0.y, r0.z, r0.w, r1.x, r1.y,
                     r1.z, r1.w, r2.x, r2.y, r2.z, r2.w};
    int oc0 = ocg * 8;
    float acc[8];
#pragma unroll
    for (int j = 0; j < 8; ++j) {
      float a0 = 0.f;
#pragma unroll
      for (int c = 0; c < 9; ++c) a0 = fmaf(in0[c], w0[(oc0 + j) * 9 + c], a0);
      acc[j] = bnrelu(a0, b0, g0, be0, m0, v0, oc0 + j);
    }
    float4* orow = (float4*)&s_h1[k * 68 + oc0];
    orow[0] = make_float4(acc[0], acc[1], acc[2], acc[3]);
    orow[1] = make_float4(acc[4], acc[5], acc[6], acc[7]);
  }
  __syncthreads();

  // ---- layer 2: 64 -> 64 ----
  {
    int oc0 = ocg * 8;
    float acc[8] = {0.f, 0.f, 0.f, 0.f, 0.f, 0.f, 0.f, 0.f};
    const float4* row = (const float4*)&s_h1[k * 68];
#pragma unroll 4
    for (int c4 = 0; c4 < 16; ++c4) {
      float4 hv = row[c4];
#pragma unroll
      for (int j = 0; j < 8; ++j) {
        float4 wv = *(const float4*)&w1[(oc0 + j) * 64 + c4 * 4];
        acc[j] = fmaf(hv.x, wv.x, acc[j]);
        acc[j] = fmaf(hv.y, wv.y, acc[j]);
        acc[j] = fmaf(hv.z, wv.z, acc[j]);
        acc[j] = fmaf(hv.w, wv.w, acc[j]);
      }
    }
#pragma unroll
    for (int j = 0; j < 8; ++j)
      acc[j] = bnrelu(acc[j], b1, g1, be1, m1, v1, oc0 + j);
    float4* orow = (float4*)&s_h2[k * 68 + oc0];
    orow[0] = make_float4(acc[0], acc[1], acc[2], acc[3]);
    orow[1] = make_float4(acc[4], acc[5], acc[6], acc[7]);
  }
  __syncthreads();

  // ---- layer 3: 64 -> 128, output into u[k][0..127]; u[k][128..130]=g ----
  {
    int oc0 = ocg * 16;
    float acc[16];
#pragma unroll
    for (int j = 0; j < 16; ++j) acc[j] = 0.f;
    const float4* row = (const float4*)&s_h2[k * 68];
#pragma unroll 2
    for (int c4 = 0; c4 < 16; ++c4) {
      float4 hv = row[c4];
#pragma unroll
      for (int j = 0; j < 16; ++j) {
        float4 wv = *(const float4*)&w2[(oc0 + j) * 64 + c4 * 4];
        acc[j] = fmaf(hv.x, wv.x, acc[j]);
        acc[j] = fmaf(hv.y, wv.y, acc[j]);
        acc[j] = fmaf(hv.z, wv.z, acc[j]);
        acc[j] = fmaf(hv.w, wv.w, acc[j]);
      }
    }
#pragma unroll
    for (int j = 0; j < 16; ++j)
      acc[j] = bnrelu(acc[j], b2, g2, be2, m2, v2, oc0 + j);
    float4* orow = (float4*)&s_u[k * 132 + oc0];
    orow[0] = make_float4(acc[0], acc[1], acc[2], acc[3]);
    orow[1] = make_float4(acc[4], acc[5], acc[6], acc[7]);
    orow[2] = make_float4(acc[8], acc[9], acc[10], acc[11]);
    orow[3] = make_float4(acc[12], acc[13], acc[14], acc[15]);
    if (t < 32) {
      s_u[t * 132 + 128] = s_nb[t * 12 + 0];
      s_u[t * 132 + 129] = s_nb[t * 12 + 1];
      s_u[t * 132 + 130] = s_nb[t * 12 + 2];
      s_u[t * 132 + 131] = 0.f;
    }
  }
  __syncthreads();

  // ---- attention ----
  {
    int oc0 = ocg * 16;
    float acc[16];
#pragma unroll
    for (int j = 0; j < 16; ++j) acc[j] = 0.f;
    const float4* urow = (const float4*)&s_u[k * 132];
    for (int r4 = 0; r4 < 33; ++r4) {
      float4 uv = urow[r4];
      int r = r4 * 4;
#pragma unroll
      for (int cc = 0; cc < 4; ++cc) {
        int rr = r + cc;
        int arow = (rr < 128) ? (rr + 3) : (rr - 128);  // rr==131 hits a[3]*0
        float uc = (cc == 0) ? uv.x : (cc == 1) ? uv.y : (cc == 2) ? uv.z : uv.w;
        const float4* arp = (const float4*)&a[arow * 128 + oc0];
#pragma unroll
        for (int j4 = 0; j4 < 4; ++j4) {
          float4 av = arp[j4];
          acc[j4 * 4 + 0] = fmaf(uc, av.x, acc[j4 * 4 + 0]);
          acc[j4 * 4 + 1] = fmaf(uc, av.y, acc[j4 * 4 + 1]);
          acc[j4 * 4 + 2] = fmaf(uc, av.z, acc[j4 * 4 + 2]);
          acc[j4 * 4 + 3] = fmaf(uc, av.w, acc[j4 * 4 + 3]);
        }
      }
    }

    float ce[16], h3[16];
#pragma unroll
    for (int j4 = 0; j4 < 4; ++j4) {
      float4 cv = *(const float4*)&ceA[(size_t)bs * 128 + oc0 + j4 * 4];
      ce[j4 * 4 + 0] = cv.x; ce[j4 * 4 + 1] = cv.y;
      ce[j4 * 4 + 2] = cv.z; ce[j4 * 4 + 3] = cv.w;
      float4 hv = *(const float4*)&s_u[k * 132 + oc0 + j4 * 4];
      h3[j4 * 4 + 0] = hv.x; h3[j4 * 4 + 1] = hv.y;
      h3[j4 * 4 + 2] = hv.z; h3[j4 * 4 + 3] = hv.w;
    }

    float* outb = out1 + (size_t)b * 128 * NS + s;
#pragma unroll
    for (int j = 0; j < 16; ++j) {
      float e = ce[j] - acc[j];
      e = (e >= 0.f) ? e : 0.2f * e;  // leaky relu, alpha=0.2
      float mx = e;
#pragma unroll
      for (int off = 16; off > 0; off >>= 1)
        mx = fmaxf(mx, __shfl_xor(mx, off));
      float p = expf(e - mx);
      float num = p * h3[j];
      float den = p;
#pragma unroll
      for (int off = 16; off > 0; off >>= 1) {
        num += __shfl_xor(num, off);
        den += __shfl_xor(den, off);
      }
      if (k == 0) outb[(size_t)(oc0 + j) * NS] = num / den;
    }
  }
}

// ---------------------------------------------------------------------------
extern "C" void kernel_launch(void* const* d_in, const int* in_sizes, int n_in,
                              void* d_out, int out_size, void* d_ws,
                              size_t ws_size, hipStream_t stream) {
  (void)in_sizes; (void)n_in; (void)out_size; (void)ws_size;
  const float* xyz = (const float*)d_in[0];
  const float* points = (const float*)d_in[1];
  const float* w0 = (const float*)d_in[2];
  const float* b0 = (const float*)d_in[3];
  const float* g0 = (const float*)d_in[4];
  const float* be0 = (const float*)d_in[5];
  const float* m0 = (const float*)d_in[6];
  const float* v0 = (const float*)d_in[7];
  const float* w1 = (const float*)d_in[8];
  const float* b1 = (const float*)d_in[9];
  const float* g1 = (const float*)d_in[10];
  const float* be1 = (const float*)d_in[11];
  const float* m1 = (const float*)d_in[12];
  const float* v1 = (const float*)d_in[13];
  const float* w2 = (const float*)d_in[14];
  const float* b2 = (const float*)d_in[15];
  const float* g2 = (const float*)d_in[16];
  const float* be2 = (const float*)d_in[17];
  const float* m2 = (const float*)d_in[18];
  const float* v2 = (const float*)d_in[19];
  const float* a = (const float*)d_in[20];

  float* out0 = (float*)d_out;                  // [B,3,S]
  float* out1 = out0 + (size_t)NB * 3 * NS;     // [B,128,S]

  int* fps = (int*)d_ws;                                   // 8192 ints
  float* nxyz = (float*)((char*)d_ws + 32768);             // 8192*3 floats
  float* ceA = (float*)((char*)d_ws + 32768 + 98304);      // 8192*128 floats

  fps_kernel<<<NB, 512, 0, stream>>>(xyz, fps, nxyz, out0);
  center_kernel<<<NB * NS, 64, 0, stream>>>(points, nxyz, fps,
      w0, b0, g0, be0, m0, v0, w1, b1, g1, be1, m1, v1,
      w2, b2, g2, be2, m2, v2, a, ceA);
  main_kernel<<<NB * NS, 256, 0, stream>>>(xyz, points, nxyz, ceA,
      w0, b0, g0, be0, m0, v0, w1, b1, g1, be1, m1, v1,
      w2, b2, g2, be2, m2, v2, a, out1);
}